// Round 2
// baseline (606.247 us; speedup 1.0000x reference)
//
#include <hip/hip_runtime.h>
#include <math.h>

#define KCUB      125
#define CROW      128          // padded C row stride (global), deg in slot 126
#define DEG_SLOT  126
#define F_OUT     32
#define GRID_DIM  32
#define NUM_VOX   (GRID_DIM * GRID_DIM * GRID_DIM)
#define LROW      132          // LDS row stride: 132 mod 32 = 4 -> conflict-free

// ---------- monotonic float<->uint encoding for atomicMax on signed floats ----
__device__ __forceinline__ unsigned int enc_f32(float f) {
    unsigned int u = __float_as_uint(f);
    return (u & 0x80000000u) ? ~u : (u | 0x80000000u);
}
__device__ __forceinline__ float dec_f32(unsigned int e) {
    return (e & 0x80000000u) ? __uint_as_float(e ^ 0x80000000u)
                             : __uint_as_float(~e);
}

// ============================ NEW PATH =======================================
// kernel 1: per-edge spline basis scatter into C[n,125] (+deg in slot 126).
// 1 thread per edge, 9 atomics (was 33 in the per-channel formulation).
__global__ __launch_bounds__(256) void edge_accum_kernel(
    const float* __restrict__ x,        // [N,1]
    const int*   __restrict__ src,      // [E]
    const int*   __restrict__ dst,      // [E]
    const float* __restrict__ pseudo,   // [E,3]
    float* __restrict__ C,              // [N,128]
    int E)
{
    int e = blockIdx.x * 256 + threadIdx.x;
    if (e >= E) return;

    float xj = x[src[e]];
    int   d  = dst[e];

    float p0 = pseudo[3 * e + 0] * 4.0f;
    float p1 = pseudo[3 * e + 1] * 4.0f;
    float p2 = pseudo[3 * e + 2] * 4.0f;

    float i0 = fminf(fmaxf(floorf(p0), 0.0f), 3.0f);
    float i1 = fminf(fmaxf(floorf(p1), 0.0f), 3.0f);
    float i2 = fminf(fmaxf(floorf(p2), 0.0f), 3.0f);
    float f0 = p0 - i0, f1 = p1 - i1, f2 = p2 - i2;
    float g0 = 1.0f - f0, g1 = 1.0f - f1, g2 = 1.0f - f2;

    int k = (int)i0 + 5 * (int)i1 + 25 * (int)i2;   // k in [0,93]
    float* row = C + (size_t)d * CROW;

    atomicAdd(row + k +  0, xj * (g0 * g1 * g2));
    atomicAdd(row + k +  1, xj * (f0 * g1 * g2));
    atomicAdd(row + k +  5, xj * (g0 * f1 * g2));
    atomicAdd(row + k +  6, xj * (f0 * f1 * g2));
    atomicAdd(row + k + 25, xj * (g0 * g1 * f2));
    atomicAdd(row + k + 26, xj * (f0 * g1 * f2));
    atomicAdd(row + k + 30, xj * (g0 * f1 * f2));
    atomicAdd(row + k + 31, xj * (f0 * f1 * f2));
    atomicAdd(row + DEG_SLOT, 1.0f);
}

// kernel 2: dense [N,125]@[125,32] + epilogue + voxel scatter-max.
// 32 nodes/block, 8 threads/node, 4 channels/thread.
__global__ __launch_bounds__(256) void node_gemm_kernel(
    const float* __restrict__ C,        // [N,128]
    const float* __restrict__ x,        // [N,1]
    const float* __restrict__ W,        // [125,32]
    const float* __restrict__ W_root,   // [32]
    const float* __restrict__ bias,     // [32]
    const float* __restrict__ pos,      // [N,3]
    unsigned int* __restrict__ pooled,  // [NUM_VOX,32] encoded
    int Nn)
{
    __shared__ float sC[32 * LROW];     // 16896 B

    int n0 = blockIdx.x * 32;
    // stage 32 rows (128 floats each) = 1024 float4, coalesced
    const float4* g = (const float4*)(C + (size_t)n0 * CROW);
    #pragma unroll
    for (int t = 0; t < 4; ++t) {
        int idx  = threadIdx.x + t * 256;   // 0..1023
        int node = idx >> 5, quad = idx & 31;
        float4 v = g[idx];
        *(float4*)&sC[node * LROW + quad * 4] = v;
    }
    __syncthreads();

    int ln = threadIdx.x >> 3;          // 0..31
    int j  = threadIdx.x & 7;           // channels 4j..4j+3
    int n  = n0 + ln;
    if (n >= Nn) return;
    const float* row = sC + ln * LROW;

    float4 acc = make_float4(0.f, 0.f, 0.f, 0.f);
    #pragma unroll 4
    for (int k4 = 0; k4 < 31; ++k4) {   // k = 0..123
        float4 r = *(const float4*)&row[k4 * 4];
        const float* wp = W + (k4 * 4) * F_OUT + 4 * j;
        float4 w0 = *(const float4*)(wp);
        float4 w1 = *(const float4*)(wp + 1 * F_OUT);
        float4 w2 = *(const float4*)(wp + 2 * F_OUT);
        float4 w3 = *(const float4*)(wp + 3 * F_OUT);
        acc.x += r.x * w0.x + r.y * w1.x + r.z * w2.x + r.w * w3.x;
        acc.y += r.x * w0.y + r.y * w1.y + r.z * w2.y + r.w * w3.y;
        acc.z += r.x * w0.z + r.y * w1.z + r.z * w2.z + r.w * w3.z;
        acc.w += r.x * w0.w + r.y * w1.w + r.z * w2.w + r.w * w3.w;
    }
    {   // k = 124
        float r = row[124];
        const float* wp = W + 124 * F_OUT + 4 * j;
        acc.x += r * wp[0]; acc.y += r * wp[1];
        acc.z += r * wp[2]; acc.w += r * wp[3];
    }

    float  dg = fmaxf(row[DEG_SLOT], 1.0f);
    float  xn = x[n];
    float4 wr = *(const float4*)(W_root + 4 * j);
    float4 bs = *(const float4*)(bias + 4 * j);

    int vx = min(max((int)floorf(pos[3 * n + 0] * (float)GRID_DIM), 0), GRID_DIM - 1);
    int vy = min(max((int)floorf(pos[3 * n + 1] * (float)GRID_DIM), 0), GRID_DIM - 1);
    int vz = min(max((int)floorf(pos[3 * n + 2] * (float)GRID_DIM), 0), GRID_DIM - 1);
    int vidx = vx + GRID_DIM * vy + GRID_DIM * GRID_DIM * vz;
    unsigned int* pv = pooled + (size_t)vidx * F_OUT + 4 * j;

    float h;
    h = acc.x / dg + xn * wr.x + bs.x; h = h > 0.f ? h : expm1f(h); atomicMax(pv + 0, enc_f32(h));
    h = acc.y / dg + xn * wr.y + bs.y; h = h > 0.f ? h : expm1f(h); atomicMax(pv + 1, enc_f32(h));
    h = acc.z / dg + xn * wr.z + bs.z; h = h > 0.f ? h : expm1f(h); atomicMax(pv + 2, enc_f32(h));
    h = acc.w / dg + xn * wr.w + bs.w; h = h > 0.f ? h : expm1f(h); atomicMax(pv + 3, enc_f32(h));
}

// kernel 3: decode, empty voxels -> 0
__global__ __launch_bounds__(256) void finalize_kernel(
    const unsigned int* __restrict__ pooled,
    float* __restrict__ out, int M)
{
    int i = blockIdx.x * blockDim.x + threadIdx.x;
    if (i >= M) return;
    unsigned int u = pooled[i];
    out[i] = (u == 0u) ? 0.0f : dec_f32(u);
}

// ============================ FALLBACK PATH (R1) =============================
__global__ __launch_bounds__(256) void edge_kernel_v1(
    const float* __restrict__ x, const int* __restrict__ src, const int* __restrict__ dst,
    const float* __restrict__ pseudo, const float* __restrict__ W,
    float* __restrict__ agg, float* __restrict__ deg, int E)
{
    __shared__ float sW[KCUB * F_OUT];
    for (int i = threadIdx.x; i < KCUB * F_OUT; i += blockDim.x) sW[i] = W[i];
    __syncthreads();

    int gid = blockIdx.x * blockDim.x + threadIdx.x;
    int e = gid >> 5, o = gid & 31;
    if (e >= E) return;

    int   d  = dst[e];
    float xj = x[src[e]];
    float p0 = pseudo[e * 3 + 0] * 4.0f, p1 = pseudo[e * 3 + 1] * 4.0f, p2 = pseudo[e * 3 + 2] * 4.0f;
    float i0 = fminf(fmaxf(floorf(p0), 0.0f), 3.0f);
    float i1 = fminf(fmaxf(floorf(p1), 0.0f), 3.0f);
    float i2 = fminf(fmaxf(floorf(p2), 0.0f), 3.0f);
    float f0 = p0 - i0, f1 = p1 - i1, f2 = p2 - i2;
    float g0 = 1.0f - f0, g1 = 1.0f - f1, g2 = 1.0f - f2;
    int base = ((int)i0 + 5 * (int)i1 + 25 * (int)i2) * F_OUT + o;

    float coeff;
    coeff  = (g0 * g1 * g2) * sW[base];
    coeff += (f0 * g1 * g2) * sW[base +  1 * F_OUT];
    coeff += (g0 * f1 * g2) * sW[base +  5 * F_OUT];
    coeff += (f0 * f1 * g2) * sW[base +  6 * F_OUT];
    coeff += (g0 * g1 * f2) * sW[base + 25 * F_OUT];
    coeff += (f0 * g1 * f2) * sW[base + 26 * F_OUT];
    coeff += (g0 * f1 * f2) * sW[base + 30 * F_OUT];
    coeff += (f0 * f1 * f2) * sW[base + 31 * F_OUT];

    atomicAdd(&agg[d * F_OUT + o], xj * coeff);
    if (o == 0) atomicAdd(&deg[d], 1.0f);
}

__global__ __launch_bounds__(256) void node_kernel_v1(
    const float* __restrict__ agg, const float* __restrict__ deg,
    const float* __restrict__ x, const float* __restrict__ W_root,
    const float* __restrict__ bias, const float* __restrict__ pos,
    unsigned int* __restrict__ pooled, int Nn)
{
    int gid = blockIdx.x * blockDim.x + threadIdx.x;
    int n = gid >> 5, o = gid & 31;
    if (n >= Nn) return;

    float dg = fmaxf(deg[n], 1.0f);
    float h  = agg[n * F_OUT + o] / dg + x[n] * W_root[o] + bias[o];
    h = (h > 0.0f) ? h : expm1f(h);

    int vx = min(max((int)floorf(pos[n * 3 + 0] * (float)GRID_DIM), 0), GRID_DIM - 1);
    int vy = min(max((int)floorf(pos[n * 3 + 1] * (float)GRID_DIM), 0), GRID_DIM - 1);
    int vz = min(max((int)floorf(pos[n * 3 + 2] * (float)GRID_DIM), 0), GRID_DIM - 1);
    int vidx = vx + GRID_DIM * vy + GRID_DIM * GRID_DIM * vz;
    atomicMax(&pooled[vidx * F_OUT + o], enc_f32(h));
}

// ============================ launcher =======================================
extern "C" void kernel_launch(void* const* d_in, const int* in_sizes, int n_in,
                              void* d_out, int out_size, void* d_ws, size_t ws_size,
                              hipStream_t stream) {
    const float* x       = (const float*)d_in[0];
    const int*   ei      = (const int*)  d_in[1];
    const float* pseudo  = (const float*)d_in[2];
    const float* pos     = (const float*)d_in[3];
    const float* W       = (const float*)d_in[4];
    const float* W_root  = (const float*)d_in[5];
    const float* bias    = (const float*)d_in[6];
    float* out = (float*)d_out;

    const int E  = in_sizes[1] / 2;
    const int Nn = in_sizes[0];          // F_IN == 1

    const size_t c_bytes      = (size_t)Nn * CROW * 4;          // 33.55 MB
    const size_t pooled_bytes = (size_t)NUM_VOX * F_OUT * 4;    // 4 MB
    const int out_elems = (out_size < NUM_VOX * F_OUT) ? out_size : NUM_VOX * F_OUT;

    if (ws_size >= c_bytes + pooled_bytes) {
        // -------- new path: 9 atomics/edge + dense GEMM --------
        float*        C      = (float*)d_ws;
        unsigned int* pooled = (unsigned int*)((char*)d_ws + c_bytes);

        hipMemsetAsync(d_ws, 0, c_bytes + pooled_bytes, stream);

        edge_accum_kernel<<<(E + 255) / 256, 256, 0, stream>>>(
            x, ei, ei + E, pseudo, C, E);
        node_gemm_kernel<<<(Nn + 31) / 32, 256, 0, stream>>>(
            C, x, W, W_root, bias, pos, pooled, Nn);
        finalize_kernel<<<(NUM_VOX * F_OUT + 255) / 256, 256, 0, stream>>>(
            pooled, out, out_elems);
    } else {
        // -------- fallback: R1 path (12.6 MB workspace) --------
        float*        agg    = (float*)d_ws;
        float*        deg    = (float*)((char*)d_ws + (size_t)Nn * F_OUT * 4);
        unsigned int* pooled = (unsigned int*)((char*)deg + (size_t)Nn * 4);
        size_t zero_bytes = (size_t)Nn * F_OUT * 4 + (size_t)Nn * 4 + pooled_bytes;

        hipMemsetAsync(d_ws, 0, zero_bytes, stream);

        edge_kernel_v1<<<(E * F_OUT + 255) / 256, 256, 0, stream>>>(
            x, ei, ei + E, pseudo, W, agg, deg, E);
        node_kernel_v1<<<(Nn * F_OUT + 255) / 256, 256, 0, stream>>>(
            agg, deg, x, W_root, bias, pos, pooled, Nn);
        finalize_kernel<<<(NUM_VOX * F_OUT + 255) / 256, 256, 0, stream>>>(
            pooled, out, out_elems);
    }
}

// Round 3
// 395.502 us; speedup vs baseline: 1.5329x; 1.5329x over previous
//
#include <hip/hip_runtime.h>
#include <math.h>

#define F_OUT     32
#define GRID_DIM  32
#define NUM_VOX   (GRID_DIM * GRID_DIM * GRID_DIM)

#define NPB    256          // nodes owned per block (fused kernel)
#define TPB_F  1024         // threads per fused block (16 waves)
#define PHASES 8
#define QCAP   1536         // per-phase LDS queue cap (expected 512, sd ~23)
#define SWS    33           // sW row stride (pad: bank = (k+d+o)&31, scattered)
#define SAS    33           // sAgg row stride (pad: bank = (rel+o)&31, scattered)

// ---------- monotonic float<->uint encoding for atomicMax on signed floats ----
__device__ __forceinline__ unsigned int enc_f32(float f) {
    unsigned int u = __float_as_uint(f);
    return (u & 0x80000000u) ? ~u : (u | 0x80000000u);
}
__device__ __forceinline__ float dec_f32(unsigned int e) {
    return (e & 0x80000000u) ? __uint_as_float(e ^ 0x80000000u)
                             : __uint_as_float(~e);
}

// ---------- kernel P: compact dst to u16, pre-gather (xj, pseudo) ------------
__global__ __launch_bounds__(256) void prep_kernel(
    const float* __restrict__ x,       // [N,1]
    const int*   __restrict__ src,     // [E]
    const int*   __restrict__ dst,     // [E]
    const float* __restrict__ pseudo,  // [E,3]
    unsigned short* __restrict__ dst16,
    float4* __restrict__ xjp,          // (xj, p0, p1, p2)
    int E)
{
    int e = blockIdx.x * 256 + threadIdx.x;
    if (e >= E) return;
    dst16[e] = (unsigned short)dst[e];              // N <= 65536
    float xj = x[src[e]];
    xjp[e] = make_float4(xj, pseudo[3 * e + 0], pseudo[3 * e + 1], pseudo[3 * e + 2]);
}

// ---------- per-edge LDS update (xj folded into the 8 corner weights) --------
__device__ __forceinline__ void process_edge(
    int e, int rel, const float4* __restrict__ xjp,
    const float* sW, float* sAgg, float* sDeg)
{
    float4 r = xjp[e];
    float xj = r.x;
    float p0 = r.y * 4.0f, p1 = r.z * 4.0f, p2 = r.w * 4.0f;
    float i0 = fminf(fmaxf(floorf(p0), 0.0f), 3.0f);
    float i1 = fminf(fmaxf(floorf(p1), 0.0f), 3.0f);
    float i2 = fminf(fmaxf(floorf(p2), 0.0f), 3.0f);
    float f0 = p0 - i0, f1 = p1 - i1, f2 = p2 - i2;
    float g0 = 1.0f - f0, g1 = 1.0f - f1, g2 = 1.0f - f2;
    int k = (int)i0 + 5 * (int)i1 + 25 * (int)i2;   // 0..93

    float w00 = g0 * g1, w10 = f0 * g1, w01 = g0 * f1, w11 = f0 * f1;
    float a2 = xj * g2, b2 = xj * f2;
    float wA0 = w00 * a2, wA1 = w10 * a2, wA2 = w01 * a2, wA3 = w11 * a2;
    float wB0 = w00 * b2, wB1 = w10 * b2, wB2 = w01 * b2, wB3 = w11 * b2;

    const float* wp = sW + k * SWS;
    float* ap = sAgg + rel * SAS;
    #pragma unroll 8
    for (int o = 0; o < F_OUT; ++o) {
        float c = wA0 * wp[o]            + wA1 * wp[1 * SWS + o]
                + wA2 * wp[5 * SWS + o]  + wA3 * wp[6 * SWS + o]
                + wB0 * wp[25 * SWS + o] + wB1 * wp[26 * SWS + o]
                + wB2 * wp[30 * SWS + o] + wB3 * wp[31 * SWS + o];
        atomicAdd(&ap[o], c);
    }
    atomicAdd(&sDeg[rel], 1.0f);
}

// ---------- kernel F: owner-block scan + LDS aggregate + epilogue ------------
__global__ __launch_bounds__(TPB_F) void fused_kernel(
    const unsigned short* __restrict__ dst16,
    const float4* __restrict__ xjp,
    const float* __restrict__ W,        // [125,32]
    const float* __restrict__ x,        // [N,1]
    const float* __restrict__ W_root,   // [32]
    const float* __restrict__ bias,     // [32]
    const float* __restrict__ pos,      // [N,3]
    unsigned int* __restrict__ pooled,  // [NUM_VOX,32] encoded
    int E, int Nn)
{
    __shared__ float sW[125 * SWS];     // 16500 B
    __shared__ float sAgg[NPB * SAS];   // 33792 B
    __shared__ float sDeg[NPB];         //  1024 B
    __shared__ int   sQ[QCAP];          //  6144 B
    __shared__ int   sQn;               // total ~57.5 KB

    const int tid = threadIdx.x;
    const int nodeBase = blockIdx.x * NPB;

    for (int i = tid; i < 125 * F_OUT; i += TPB_F)
        sW[(i >> 5) * SWS + (i & 31)] = W[i];
    for (int i = tid; i < NPB * SAS; i += TPB_F) sAgg[i] = 0.0f;
    for (int i = tid; i < NPB; i += TPB_F) sDeg[i] = 0.0f;

    const int iters = (E + PHASES * TPB_F * 8 - 1) / (PHASES * TPB_F * 8);

    for (int p = 0; p < PHASES; ++p) {
        if (tid == 0) sQn = 0;
        __syncthreads();                 // covers init on p==0 too

        // ---- scan my slice of edges (8 u16 dsts per 16B load) ----
        for (int it = 0; it < iters; ++it) {
            int e0 = (((p * iters + it) * TPB_F) + tid) * 8;
            if (e0 >= E) continue;
            unsigned short d[8];
            if (e0 + 8 <= E) {
                int4 raw = *(const int4*)(dst16 + e0);
                unsigned int a = (unsigned int)raw.x, b = (unsigned int)raw.y,
                             c = (unsigned int)raw.z, q = (unsigned int)raw.w;
                d[0] = a & 0xFFFFu; d[1] = a >> 16;
                d[2] = b & 0xFFFFu; d[3] = b >> 16;
                d[4] = c & 0xFFFFu; d[5] = c >> 16;
                d[6] = q & 0xFFFFu; d[7] = q >> 16;
            } else {
                for (int j = 0; j < 8; ++j)
                    d[j] = (e0 + j < E) ? dst16[e0 + j] : 0xFFFFu;
            }
            #pragma unroll
            for (int j = 0; j < 8; ++j) {
                int rel = (int)d[j] - nodeBase;
                if ((unsigned)rel < (unsigned)NPB) {
                    int pos_q = atomicAdd(&sQn, 1);
                    if (pos_q < QCAP) sQ[pos_q] = ((e0 + j) << 8) | rel;  // E < 2^23
                    else process_edge(e0 + j, rel, xjp, sW, sAgg, sDeg);  // overflow (rare)
                }
            }
        }
        __syncthreads();

        // ---- drain queue: one lane per edge, LDS atomics only ----
        int nq = sQn; if (nq > QCAP) nq = QCAP;
        for (int qb = 0; qb < nq; qb += TPB_F) {
            int qi = qb + tid;
            if (qi < nq) {
                int pk = sQ[qi];
                process_edge(pk >> 8, pk & 255, xjp, sW, sAgg, sDeg);
            }
        }
        __syncthreads();
    }

    // ---- epilogue: mean + root + bias + ELU + voxel scatter-max ----
    for (int item = tid; item < NPB * F_OUT; item += TPB_F) {
        int nr = item >> 5, o = item & 31;
        int n = nodeBase + nr;
        if (n >= Nn) break;
        float dg = fmaxf(sDeg[nr], 1.0f);
        float h = sAgg[nr * SAS + o] / dg + x[n] * W_root[o] + bias[o];
        h = (h > 0.0f) ? h : expm1f(h);

        int vx = min(max((int)floorf(pos[3 * n + 0] * (float)GRID_DIM), 0), GRID_DIM - 1);
        int vy = min(max((int)floorf(pos[3 * n + 1] * (float)GRID_DIM), 0), GRID_DIM - 1);
        int vz = min(max((int)floorf(pos[3 * n + 2] * (float)GRID_DIM), 0), GRID_DIM - 1);
        int vidx = vx + GRID_DIM * vy + GRID_DIM * GRID_DIM * vz;
        atomicMax(&pooled[(size_t)vidx * F_OUT + o], enc_f32(h));
    }
}

// ---------- kernel Z: decode, empty voxels -> 0 ------------------------------
__global__ __launch_bounds__(256) void finalize_kernel(
    const unsigned int* __restrict__ pooled,
    float* __restrict__ out, int M)
{
    int i = blockIdx.x * blockDim.x + threadIdx.x;
    if (i >= M) return;
    unsigned int u = pooled[i];
    out[i] = (u == 0u) ? 0.0f : dec_f32(u);
}

// ============================ launcher =======================================
extern "C" void kernel_launch(void* const* d_in, const int* in_sizes, int n_in,
                              void* d_out, int out_size, void* d_ws, size_t ws_size,
                              hipStream_t stream) {
    const float* x       = (const float*)d_in[0];
    const int*   ei      = (const int*)  d_in[1];
    const float* pseudo  = (const float*)d_in[2];
    const float* pos     = (const float*)d_in[3];
    const float* W       = (const float*)d_in[4];
    const float* W_root  = (const float*)d_in[5];
    const float* bias    = (const float*)d_in[6];
    float* out = (float*)d_out;

    const int E  = in_sizes[1] / 2;
    const int Nn = in_sizes[0];          // F_IN == 1, Nn <= 65536 (fits u16)

    // workspace: [pooled 4MB][dst16 2MB][xjp 16MB]
    unsigned int*   pooled = (unsigned int*)d_ws;
    unsigned short* dst16  = (unsigned short*)((char*)d_ws + (size_t)NUM_VOX * F_OUT * 4);
    float4*         xjp    = (float4*)((char*)dst16 + 2u * 1024 * 1024);

    hipMemsetAsync(pooled, 0, (size_t)NUM_VOX * F_OUT * 4, stream);

    prep_kernel<<<(E + 255) / 256, 256, 0, stream>>>(
        x, ei, ei + E, pseudo, dst16, xjp, E);

    fused_kernel<<<(Nn + NPB - 1) / NPB, TPB_F, 0, stream>>>(
        dst16, xjp, W, x, W_root, bias, pos, pooled, E, Nn);

    const int M = (out_size < NUM_VOX * F_OUT) ? out_size : NUM_VOX * F_OUT;
    finalize_kernel<<<(M + 255) / 256, 256, 0, stream>>>(pooled, out, M);
}

// Round 4
// 216.582 us; speedup vs baseline: 2.7992x; 1.8261x over previous
//
#include <hip/hip_runtime.h>
#include <math.h>

#define F_OUT     32
#define GRID_DIM  32
#define NUM_VOX   (GRID_DIM * GRID_DIM * GRID_DIM)

#define NPB       128        // nodes per owner block; bucket = dst >> 7
#define NB_MAX    1024       // max buckets supported (Nn <= 131072)
#define EB        2048       // edges per scatter block
#define SCS       127        // sC row stride: 127&31=31 -> GEMM column reads conflict-free

// ---------- monotonic float<->uint encoding for atomicMax on signed floats ----
__device__ __forceinline__ unsigned int enc_f32(float f) {
    unsigned int u = __float_as_uint(f);
    return (u & 0x80000000u) ? ~u : (u | 0x80000000u);
}
__device__ __forceinline__ float dec_f32(unsigned int e) {
    return (e & 0x80000000u) ? __uint_as_float(e ^ 0x80000000u)
                             : __uint_as_float(~e);
}

// ---------- K1: bucket histogram ---------------------------------------------
__global__ __launch_bounds__(256) void hist_kernel(
    const int* __restrict__ dst, int* __restrict__ hist, int E)
{
    __shared__ int sh[NB_MAX];
    for (int i = threadIdx.x; i < NB_MAX; i += 256) sh[i] = 0;
    __syncthreads();
    int stride = gridDim.x * 256;
    for (int e = blockIdx.x * 256 + threadIdx.x; e < E; e += stride)
        atomicAdd(&sh[dst[e] >> 7], 1);
    __syncthreads();
    for (int i = threadIdx.x; i < NB_MAX; i += 256) {
        int v = sh[i];
        if (v) atomicAdd(&hist[i], v);
    }
}

// ---------- K2: exclusive prefix + cursor init (single block) ----------------
__global__ __launch_bounds__(NB_MAX) void prefix_kernel(
    const int* __restrict__ hist, int* __restrict__ bases,
    int* __restrict__ cursor, int nb)
{
    __shared__ int s[NB_MAX];
    int tid = threadIdx.x;
    int v = hist[tid];
    s[tid] = v;
    __syncthreads();
    for (int off = 1; off < NB_MAX; off <<= 1) {
        int t = (tid >= off) ? s[tid - off] : 0;
        __syncthreads();
        s[tid] += t;
        __syncthreads();
    }
    int excl = s[tid] - v;
    bases[tid] = excl;
    if (tid == NB_MAX - 1) bases[NB_MAX] = s[tid];
    if (tid < nb) cursor[tid * 16] = excl;   // 64B-padded cursors
}

// ---------- K3: scatter edges into buckets -----------------------------------
__global__ __launch_bounds__(256) void scatter_kernel(
    const float* __restrict__ x, const int* __restrict__ src,
    const int* __restrict__ dst, const float* __restrict__ pseudo,
    int* __restrict__ cursor, float4* __restrict__ payload,
    unsigned char* __restrict__ rel8, int E)
{
    int e_lo = blockIdx.x * EB;
    int e_hi = e_lo + EB; if (e_hi > E) e_hi = E;
    for (int e = e_lo + threadIdx.x; e < e_hi; e += 256) {
        int d = dst[e];
        int slot = atomicAdd(&cursor[(d >> 7) * 16], 1);
        float xj = x[src[e]];
        payload[slot] = make_float4(xj, pseudo[3 * e], pseudo[3 * e + 1], pseudo[3 * e + 2]);
        rel8[slot] = (unsigned char)(d & 127);
    }
}

// ---------- K4: owner block — LDS accumulate C, dense GEMM, epilogue ---------
__global__ __launch_bounds__(512) void owner_kernel(
    const float4* __restrict__ payload, const unsigned char* __restrict__ rel8,
    const int* __restrict__ bases, const float* __restrict__ W,
    const float* __restrict__ x, const float* __restrict__ W_root,
    const float* __restrict__ bias, const float* __restrict__ pos,
    unsigned int* __restrict__ pooled, int Nn)
{
    __shared__ float sC[NPB * SCS];    // 65,024 B
    const int tid = threadIdx.x;
    const int n0  = blockIdx.x * NPB;

    for (int i = tid; i < NPB * SCS; i += 512) sC[i] = 0.0f;
    __syncthreads();

    // ---- accumulate basis coefficients: 9 LDS atomics per edge ----
    int base = bases[blockIdx.x], end = bases[blockIdx.x + 1];
    for (int i = base + tid; i < end; i += 512) {
        float4 r  = payload[i];
        int   rel = rel8[i];
        float xj = r.x;
        float p0 = r.y * 4.0f, p1 = r.z * 4.0f, p2 = r.w * 4.0f;
        float i0 = fminf(fmaxf(floorf(p0), 0.0f), 3.0f);
        float i1 = fminf(fmaxf(floorf(p1), 0.0f), 3.0f);
        float i2 = fminf(fmaxf(floorf(p2), 0.0f), 3.0f);
        float f0 = p0 - i0, f1 = p1 - i1, f2 = p2 - i2;
        float g0 = 1.0f - f0, g1 = 1.0f - f1, g2 = 1.0f - f2;
        int k = (int)i0 + 5 * (int)i1 + 25 * (int)i2;    // 0..93

        float w00 = g0 * g1, w10 = f0 * g1, w01 = g0 * f1, w11 = f0 * f1;
        float a2 = xj * g2, b2 = xj * f2;
        float* row = sC + rel * SCS;
        atomicAdd(row + k +  0, w00 * a2);
        atomicAdd(row + k +  1, w10 * a2);
        atomicAdd(row + k +  5, w01 * a2);
        atomicAdd(row + k +  6, w11 * a2);
        atomicAdd(row + k + 25, w00 * b2);
        atomicAdd(row + k + 26, w10 * b2);
        atomicAdd(row + k + 30, w01 * b2);
        atomicAdd(row + k + 31, w11 * b2);
        atomicAdd(row + 125, 1.0f);                      // degree
    }
    __syncthreads();

    // ---- dense GEMM: [128 x 125] @ [125 x 32], 8 channels/thread ----
    int node = tid & (NPB - 1);
    int cg   = tid >> 7;                 // wave-uniform channel group (0..3)
    const float* crow = sC + node * SCS;
    float acc[8] = {0.f, 0.f, 0.f, 0.f, 0.f, 0.f, 0.f, 0.f};
    #pragma unroll 5
    for (int k = 0; k < 125; ++k) {
        float r = crow[k];
        const float4* w4 = (const float4*)(W + k * F_OUT + cg * 8);
        float4 wa = w4[0], wb = w4[1];
        acc[0] += r * wa.x; acc[1] += r * wa.y; acc[2] += r * wa.z; acc[3] += r * wa.w;
        acc[4] += r * wb.x; acc[5] += r * wb.y; acc[6] += r * wb.z; acc[7] += r * wb.w;
    }
    float dg = fmaxf(crow[125], 1.0f);
    int   n  = n0 + node;
    float xn = (n < Nn) ? x[n] : 0.0f;
    __syncthreads();                     // all sC reads done

    // ---- epilogue into sC (reuse slots 0..31 as h[node][o]) ----
    if (n < Nn) {
        #pragma unroll
        for (int c = 0; c < 8; ++c) {
            int o = cg * 8 + c;
            float h = acc[c] / dg + xn * W_root[o] + bias[o];
            h = (h > 0.0f) ? h : expm1f(h);
            sC[node * SCS + o] = h;
        }
    }
    __syncthreads();

    // ---- voxel scatter-max, channel-coalesced (o = lane&31) ----
    for (int item = tid; item < NPB * F_OUT; item += 512) {
        int nr = item >> 5, o = item & 31;
        int nn = n0 + nr;
        if (nn >= Nn) break;
        int vx = min(max((int)floorf(pos[3 * nn + 0] * (float)GRID_DIM), 0), GRID_DIM - 1);
        int vy = min(max((int)floorf(pos[3 * nn + 1] * (float)GRID_DIM), 0), GRID_DIM - 1);
        int vz = min(max((int)floorf(pos[3 * nn + 2] * (float)GRID_DIM), 0), GRID_DIM - 1);
        int vidx = vx + GRID_DIM * vy + GRID_DIM * GRID_DIM * vz;
        atomicMax(&pooled[(size_t)vidx * F_OUT + o], enc_f32(sC[nr * SCS + o]));
    }
}

// ---------- K5: decode, empty voxels -> 0 ------------------------------------
__global__ __launch_bounds__(256) void finalize_kernel(
    const unsigned int* __restrict__ pooled,
    float* __restrict__ out, int M)
{
    int i = blockIdx.x * blockDim.x + threadIdx.x;
    if (i >= M) return;
    unsigned int u = pooled[i];
    out[i] = (u == 0u) ? 0.0f : dec_f32(u);
}

// ============================ launcher =======================================
extern "C" void kernel_launch(void* const* d_in, const int* in_sizes, int n_in,
                              void* d_out, int out_size, void* d_ws, size_t ws_size,
                              hipStream_t stream) {
    const float* x       = (const float*)d_in[0];
    const int*   ei      = (const int*)  d_in[1];
    const float* pseudo  = (const float*)d_in[2];
    const float* pos     = (const float*)d_in[3];
    const float* W       = (const float*)d_in[4];
    const float* W_root  = (const float*)d_in[5];
    const float* bias    = (const float*)d_in[6];
    float* out = (float*)d_out;

    const int E  = in_sizes[1] / 2;
    const int Nn = in_sizes[0];                       // F_IN == 1
    const int nb = (Nn + NPB - 1) / NPB;              // buckets (512 here)

    // workspace layout (all offsets 256B-aligned where it matters):
    // [pooled 4MB][hist 4352B][bases 4352B][cursor 64KB][payload E*16][rel8 E]
    char* wsb = (char*)d_ws;
    unsigned int*  pooled  = (unsigned int*)wsb;
    size_t off = (size_t)NUM_VOX * F_OUT * 4;         // 4,194,304
    int*           hist    = (int*)(wsb + off);  off += 4352;
    int*           bases   = (int*)(wsb + off);  off += 4352;
    int*           cursor  = (int*)(wsb + off);  off += (size_t)NB_MAX * 16 * 4;
    float4*        payload = (float4*)(wsb + off); off += (size_t)E * 16;
    unsigned char* rel8    = (unsigned char*)(wsb + off);

    // zero pooled + hist (contiguous)
    hipMemsetAsync(d_ws, 0, (size_t)NUM_VOX * F_OUT * 4 + 4352, stream);

    hist_kernel<<<256, 256, 0, stream>>>(ei + E, hist, E);
    prefix_kernel<<<1, NB_MAX, 0, stream>>>(hist, bases, cursor, nb);
    scatter_kernel<<<(E + EB - 1) / EB, 256, 0, stream>>>(
        x, ei, ei + E, pseudo, cursor, payload, rel8, E);
    owner_kernel<<<nb, 512, 0, stream>>>(
        payload, rel8, bases, W, x, W_root, bias, pos, pooled, Nn);

    const int M = (out_size < NUM_VOX * F_OUT) ? out_size : NUM_VOX * F_OUT;
    finalize_kernel<<<(M + 255) / 256, 256, 0, stream>>>(pooled, out, M);
}